// Round 8
// baseline (273.946 us; speedup 1.0000x reference)
//
#include <hip/hip_runtime.h>

// AttentionBlock: B=16, C=512, H=W=32 (T=1024), 8 heads, head_dim=64, fp32 in/out.
// R8: GEMMs get the attn treatment: 2-phase double-buffered staging (1 barrier
// per K-step), gemm0+gemm1 merged into one k_qkv launch (1536 blocks), and
// bijective XCD swizzle on both GEMM kernels. k_attn: + s_setprio around MFMA.

#define TSZ 1024
#define CCH 512
#define NBATCH 16

typedef __attribute__((ext_vector_type(8))) short short8;
typedef __attribute__((ext_vector_type(4))) float f32x4;
typedef __attribute__((ext_vector_type(4))) int i32x4;
typedef __attribute__((ext_vector_type(4))) unsigned u32x4;
typedef __attribute__((ext_vector_type(2))) unsigned u32x2;

__device__ inline short f2bf(float f) {
  unsigned u = __builtin_bit_cast(unsigned, f);
  u += 0x7fff + ((u >> 16) & 1);   // round-to-nearest-even
  return (short)(u >> 16);
}

__device__ inline void gl16(const void* g, void* l) {
  __builtin_amdgcn_global_load_lds((const __attribute__((address_space(1))) void*)g,
                                   (__attribute__((address_space(3))) void*)l,
                                   16, 0, 0);
}

// ---------------- weight fp32 -> bf16 ----------------
__global__ __launch_bounds__(256) void k_cvt(const float* __restrict__ wq,
                                             const float* __restrict__ wp,
                                             short* __restrict__ wqb,
                                             short* __restrict__ wpb) {
  int i = blockIdx.x * 256 + threadIdx.x;
  const int nq = 1536 * 512;
  if (i < nq) wqb[i] = f2bf(wq[i]);
  int j = i - nq;
  if (j >= 0 && j < 512 * 512) wpb[j] = f2bf(wp[j]);
}

// ---------------- LayerNorm over C + transpose to xnT[b][t][c] (bf16) ----------------
__global__ __launch_bounds__(256) void k_ln(const float* __restrict__ x,
                                            short* __restrict__ xnT) {
  const int b = blockIdx.x;
  const int t0 = blockIdx.y * 64;
  const int tid = threadIdx.x;
  const int tt = tid & 63, cg = tid >> 6;

  __shared__ float red[2][4][64];
  __shared__ float mu_s[64], rs_s[64];
  __shared__ float xt[64][65];   // +1 pad -> conflict-free transpose

  const float* xb = x + (long)b * CCH * TSZ;

  float s = 0.f, s2 = 0.f;
  for (int c = cg * 128; c < cg * 128 + 128; ++c) {
    float v = xb[(long)c * TSZ + t0 + tt];
    s += v; s2 += v * v;
  }
  red[0][cg][tt] = s; red[1][cg][tt] = s2;
  __syncthreads();
  if (tid < 64) {
    float ss = red[0][0][tid] + red[0][1][tid] + red[0][2][tid] + red[0][3][tid];
    float qq = red[1][0][tid] + red[1][1][tid] + red[1][2][tid] + red[1][3][tid];
    float mu = ss * (1.f / 512.f);
    float var = qq * (1.f / 512.f) - mu * mu;
    mu_s[tid] = mu;
    rs_s[tid] = rsqrtf(var + 1e-5f);
  }
  __syncthreads();

  for (int c0 = 0; c0 < CCH; c0 += 64) {
    for (int i = tid; i < 64 * 64; i += 256) {
      int ci = i >> 6, t2 = i & 63;
      xt[ci][t2] = xb[(long)(c0 + ci) * TSZ + t0 + t2];
    }
    __syncthreads();
    for (int i = tid; i < 64 * 64; i += 256) {
      int cc = i & 63, t2 = i >> 6;
      float v = (xt[cc][t2] - mu_s[t2]) * rs_s[t2];
      xnT[((long)b * TSZ + t0 + t2) * CCH + c0 + cc] = f2bf(v);
    }
    __syncthreads();
  }
}

// ---------------- head-aware W-row maps ----------------
__device__ inline int qkmap(int n) {        // qk output col -> w_qkv row
  if (n < 512) return (n >> 6) * 192 + (n & 63);          // q
  int j = n - 512;
  return (j >> 6) * 192 + 64 + (j & 63);                  // k
}
__device__ inline int vmap(int m) {         // v output row -> w_qkv row
  return (m >> 6) * 192 + 128 + (m & 63);
}

// ---------------- merged QKV GEMM (dbuf, XCD swizzle) ----------------
// 1536 blocks: wg<64 -> qk = xnT x Wqk^T (bf16 out[b][t][1024], q scaled, +bias)
//              wg>=64 -> v = Wv x xnT^T  (bf16 out[b][512][1024], +bias)
__global__ __launch_bounds__(256) void k_qkv(const short* __restrict__ xnT,
                                             const short* __restrict__ wqb,
                                             short* __restrict__ qkb,
                                             short* __restrict__ vbuf,
                                             const float* __restrict__ bias) {
  const int d = blockIdx.y * 96 + blockIdx.x;            // 0..1535, x fastest
  const int orig = (d & 7) * 192 + (d >> 3);             // bijective XCD swizzle
  const int z = orig / 96, wg = orig % 96;
  const bool qkmode = wg < 64;
  const int wgg = qkmode ? wg : wg - 64;
  const int m0 = (wgg >> 3) * 128, n0 = (wgg & 7) * 128;

  const int tid = threadIdx.x;
  const int lane = tid & 63, wv = tid >> 6;
  const int wm = wv >> 1, wn = wv & 1;
  const int l15 = lane & 15, lg = lane >> 4;

  const short* A = qkmode ? xnT + (long)z * TSZ * CCH : wqb;
  const short* Bm = qkmode ? wqb : xnT + (long)z * TSZ * CCH;

  __shared__ __attribute__((aligned(16))) short sA[2][128 * 32];
  __shared__ __attribute__((aligned(16))) short sB[2][128 * 32];

  f32x4 acc[4][4];
#pragma unroll
  for (int i = 0; i < 4; ++i)
#pragma unroll
    for (int j = 0; j < 4; ++j) acc[i][j] = (f32x4){0.f, 0.f, 0.f, 0.f};

  long a_src[2], b_src[2];
#pragma unroll
  for (int q = 0; q < 2; ++q) {
    int idx = wv * 128 + q * 64 + lane;      // 16B chunk id, 512 total per tile
    int row = idx >> 2, kc = (idx & 3) * 8;  // 4 chunks per 32-elem row
    int ar = qkmode ? (m0 + row) : vmap(m0 + row);
    a_src[q] = (long)ar * CCH + kc;
    int br = qkmode ? qkmap(n0 + row) : (n0 + row);
    b_src[q] = (long)br * CCH + kc;
  }

#define GSTAGE(buf, k0s)                                                       \
  {                                                                            \
    _Pragma("unroll") for (int q = 0; q < 2; ++q) {                            \
      gl16(A + a_src[q] + (k0s), sA[buf] + (wv * 128 + q * 64) * 8);           \
      gl16(Bm + b_src[q] + (k0s), sB[buf] + (wv * 128 + q * 64) * 8);          \
    }                                                                          \
  }

  GSTAGE(0, 0);
  __syncthreads();

  for (int k0 = 0; k0 < CCH; k0 += 32) {
    const int cur = (k0 >> 5) & 1;
    if (k0 + 32 < CCH) GSTAGE(cur ^ 1, k0 + 32);   // prefetch next K-tile
    short8 af[4], bfr[4];
#pragma unroll
    for (int i = 0; i < 4; ++i)
      af[i] = *(const short8*)(sA[cur] + ((wm * 64 + i * 16 + l15) * 32 + lg * 8));
#pragma unroll
    for (int j = 0; j < 4; ++j)
      bfr[j] = *(const short8*)(sB[cur] + ((wn * 64 + j * 16 + l15) * 32 + lg * 8));
    __builtin_amdgcn_s_setprio(1);
#pragma unroll
    for (int i = 0; i < 4; ++i)
#pragma unroll
      for (int j = 0; j < 4; ++j)
        acc[i][j] = __builtin_amdgcn_mfma_f32_16x16x32_bf16(af[i], bfr[j], acc[i][j], 0, 0, 0);
    __builtin_amdgcn_s_setprio(0);
    __syncthreads();   // drains prefetch; next iter reads cur^1
  }

#pragma unroll
  for (int i = 0; i < 4; ++i)
#pragma unroll
    for (int j = 0; j < 4; ++j)
#pragma unroll
      for (int r = 0; r < 4; ++r) {
        int mi = m0 + wm * 64 + i * 16 + lg * 4 + r;
        int ni = n0 + wn * 64 + j * 16 + l15;
        float val = acc[i][j][r];
        long o = (long)mi * TSZ + ni;
        if (qkmode) {
          val += bias[qkmap(ni)];
          // fold scale^2=1/8 AND log2(e) into q (post-bias, as ref)
          if (ni < 512) val *= 0.18033688011112042f;   // 0.125 * log2(e)
          qkb[(long)z * TSZ * TSZ + o] = f2bf(val);
        } else {
          val += bias[vmap(mi)];
          vbuf[(long)z * CCH * TSZ + o] = f2bf(val);
        }
      }
}

// ---------------- proj GEMM: out = Wp x hb^T + bias + resid (fp32) ----------------
__global__ __launch_bounds__(256) void k_proj(const short* __restrict__ wpb,
                                              const short* __restrict__ hbuf,
                                              float* __restrict__ outp,
                                              const float* __restrict__ bias,
                                              const float* __restrict__ resid) {
  const int d = blockIdx.y * 32 + blockIdx.x;            // 0..511
  const int orig = (d & 7) * 64 + (d >> 3);              // bijective XCD swizzle
  const int z = orig / 32, wg = orig % 32;
  const int m0 = (wg >> 3) * 128, n0 = (wg & 7) * 128;

  const int tid = threadIdx.x;
  const int lane = tid & 63, wv = tid >> 6;
  const int wm = wv >> 1, wn = wv & 1;
  const int l15 = lane & 15, lg = lane >> 4;

  const short* A = wpb;
  const short* Bm = hbuf + (long)z * TSZ * CCH;

  __shared__ __attribute__((aligned(16))) short sA[2][128 * 32];
  __shared__ __attribute__((aligned(16))) short sB[2][128 * 32];

  f32x4 acc[4][4];
#pragma unroll
  for (int i = 0; i < 4; ++i)
#pragma unroll
    for (int j = 0; j < 4; ++j) acc[i][j] = (f32x4){0.f, 0.f, 0.f, 0.f};

  long a_src[2], b_src[2];
#pragma unroll
  for (int q = 0; q < 2; ++q) {
    int idx = wv * 128 + q * 64 + lane;
    int row = idx >> 2, kc = (idx & 3) * 8;
    a_src[q] = (long)(m0 + row) * CCH + kc;
    b_src[q] = (long)(n0 + row) * CCH + kc;
  }

  GSTAGE(0, 0);
  __syncthreads();

  for (int k0 = 0; k0 < CCH; k0 += 32) {
    const int cur = (k0 >> 5) & 1;
    if (k0 + 32 < CCH) GSTAGE(cur ^ 1, k0 + 32);
    short8 af[4], bfr[4];
#pragma unroll
    for (int i = 0; i < 4; ++i)
      af[i] = *(const short8*)(sA[cur] + ((wm * 64 + i * 16 + l15) * 32 + lg * 8));
#pragma unroll
    for (int j = 0; j < 4; ++j)
      bfr[j] = *(const short8*)(sB[cur] + ((wn * 64 + j * 16 + l15) * 32 + lg * 8));
    __builtin_amdgcn_s_setprio(1);
#pragma unroll
    for (int i = 0; i < 4; ++i)
#pragma unroll
      for (int j = 0; j < 4; ++j)
        acc[i][j] = __builtin_amdgcn_mfma_f32_16x16x32_bf16(af[i], bfr[j], acc[i][j], 0, 0, 0);
    __builtin_amdgcn_s_setprio(0);
    __syncthreads();
  }

#pragma unroll
  for (int i = 0; i < 4; ++i)
#pragma unroll
    for (int j = 0; j < 4; ++j)
#pragma unroll
      for (int r = 0; r < 4; ++r) {
        int mi = m0 + wm * 64 + i * 16 + lg * 4 + r;
        int ni = n0 + wn * 64 + j * 16 + l15;
        long o = (long)z * CCH * TSZ + (long)mi * TSZ + ni;
        outp[o] = acc[i][j][r] + bias[mi] + resid[o];
      }
}

// ---------------- flash attention ----------------
// no-max softmax, swapped QK, dbuf staging, XCD swizzle, P->PV via k-slot
// permutation (pure register), V sigma-permuted in LDS via reg-staging.
// R8: + s_setprio around MFMA clusters.
__global__ __launch_bounds__(256, 4) void k_attn(const short* __restrict__ qk,
                                                 const short* __restrict__ vbuf,
                                                 short* __restrict__ hb) {
  const int wgid = blockIdx.y * gridDim.x + blockIdx.x;   // 0..1023, x fastest
  const int xcd = wgid & 7, kb = wgid >> 3;
  const int bh = xcd * 16 + (kb & 15);                    // 16 bh per XCD
  const int t0 = (kb >> 4) * 128;
  const int b = bh >> 3, h = bh & 7;
  const int tid = threadIdx.x;
  const int lane = tid & 63, w = tid >> 6;
  const int l15 = lane & 15, lg = lane >> 4;

  __shared__ __attribute__((aligned(16))) short kt[2][64 * 64];   // [s][c], XOR swizzled
  __shared__ __attribute__((aligned(16))) short vt[2][64 * 64];   // [c][s'], sigma + swizzled

  const short* qkb = qk + (long)b * TSZ * 1024;
  const short* vb = vbuf + (long)b * CCH * TSZ;

  short8 aq[2][2];
  {
    const short* qb = qkb + (long)(t0 + w * 32) * 1024 + h * 64;
#pragma unroll
    for (int jt = 0; jt < 2; ++jt)
#pragma unroll
      for (int kk = 0; kk < 2; ++kk)
        aq[jt][kk] = *(const short8*)(qb + (long)(jt * 16 + l15) * 1024 + kk * 32 + lg * 8);
  }

  f32x4 of[2][4];
  float lp[2] = {0.f, 0.f};
#pragma unroll
  for (int i = 0; i < 2; ++i)
#pragma unroll
    for (int nf = 0; nf < 4; ++nf) of[i][nf] = (f32x4){0.f, 0.f, 0.f, 0.f};

  int srow[2], scoff[2];
#pragma unroll
  for (int q = 0; q < 2; ++q) {
    int idx = w * 128 + q * 64 + lane;
    int row = idx >> 3;
    int byo = ((idx & 7) * 16) ^ ((row & 7) << 4);
    srow[q] = row;
    scoff[q] = byo >> 1;
  }

  long vsrc[2];
  int vdstA[2], vdstB[2];
#pragma unroll
  for (int q = 0; q < 2; ++q) {
    int idx = q * 256 + tid;
    int c = idx >> 3, s8 = (idx & 7) * 8;
    vsrc[q] = (long)(h * 64 + c) * TSZ + s8;
    int kk2 = s8 >> 5, h4 = (s8 >> 4) & 1, lgf0 = (s8 & 15) >> 2;
    int spA = kk2 * 32 + lgf0 * 8 + h4 * 4;
    vdstA[q] = ((c * 64 + spA) * 2) ^ ((c & 7) << 4);
    vdstB[q] = ((c * 64 + spA + 8) * 2) ^ ((c & 7) << 4);
  }

#define STAGE_K(buf, s0s)                                                      \
  {                                                                            \
    _Pragma("unroll") for (int q = 0; q < 2; ++q)                              \
      gl16(qkb + (long)((s0s) + srow[q]) * 1024 + 512 + h * 64 + scoff[q],     \
           kt[buf] + (w * 128 + q * 64) * 8);                                  \
  }

  u32x4 vreg0 = *(const u32x4*)(vb + vsrc[0]);
  u32x4 vreg1 = *(const u32x4*)(vb + vsrc[1]);
  STAGE_K(0, 0);
  *(u32x2*)((char*)vt[0] + vdstA[0]) = (u32x2){vreg0.x, vreg0.y};
  *(u32x2*)((char*)vt[0] + vdstB[0]) = (u32x2){vreg0.z, vreg0.w};
  *(u32x2*)((char*)vt[0] + vdstA[1]) = (u32x2){vreg1.x, vreg1.y};
  *(u32x2*)((char*)vt[0] + vdstB[1]) = (u32x2){vreg1.z, vreg1.w};
  __syncthreads();

  for (int s0 = 0; s0 < TSZ; s0 += 64) {
    const int cur = (s0 >> 6) & 1;
    const bool np = (s0 + 64 < TSZ);
    if (np) {
      vreg0 = *(const u32x4*)(vb + vsrc[0] + s0 + 64);
      vreg1 = *(const u32x4*)(vb + vsrc[1] + s0 + 64);
      STAGE_K(cur ^ 1, s0 + 64);
    }

    // S^T = K Q^T via mfma(K,Q)
    f32x4 sf[2][4];
#pragma unroll
    for (int jt = 0; jt < 2; ++jt)
#pragma unroll
      for (int ms = 0; ms < 4; ++ms) sf[jt][ms] = (f32x4){0.f, 0.f, 0.f, 0.f};
    __builtin_amdgcn_s_setprio(1);
#pragma unroll
    for (int kk = 0; kk < 2; ++kk)
#pragma unroll
      for (int ms = 0; ms < 4; ++ms) {
        int srw = ms * 16 + l15;
        int byo = ((srw * 64 + kk * 32 + lg * 8) * 2) ^ ((srw & 7) << 4);
        short8 ka = *(const short8*)((const char*)kt[cur] + byo);
#pragma unroll
        for (int jt = 0; jt < 2; ++jt)
          sf[jt][ms] = __builtin_amdgcn_mfma_f32_16x16x32_bf16(ka, aq[jt][kk], sf[jt][ms], 0, 0, 0);
      }
    __builtin_amdgcn_s_setprio(0);

    // p = 2^s; denom in-lane; cvt_pk pairs ARE the PV A-fragment under pi.
    short8 apf[2][2];
#pragma unroll
    for (int jt = 0; jt < 2; ++jt) {
      float p[4][4];
#pragma unroll
      for (int ms = 0; ms < 4; ++ms)
#pragma unroll
        for (int r = 0; r < 4; ++r)
          p[ms][r] = exp2f(sf[jt][ms][r]);
#pragma unroll
      for (int ms = 0; ms < 4; ++ms)
        lp[jt] += (p[ms][0] + p[ms][1]) + (p[ms][2] + p[ms][3]);
      unsigned pk[4][2];
#pragma unroll
      for (int ms = 0; ms < 4; ++ms)
#pragma unroll
        for (int u = 0; u < 2; ++u)
          asm("v_cvt_pk_bf16_f32 %0, %1, %2" : "=v"(pk[ms][u])
              : "v"(p[ms][2 * u]), "v"(p[ms][2 * u + 1]));
#pragma unroll
      for (int kk = 0; kk < 2; ++kk) {
        i32x4 a32 = (i32x4){(int)pk[2 * kk][0], (int)pk[2 * kk][1],
                            (int)pk[2 * kk + 1][0], (int)pk[2 * kk + 1][1]};
        apf[jt][kk] = __builtin_bit_cast(short8, a32);
      }
    }

    // O += P V^T
    __builtin_amdgcn_s_setprio(1);
#pragma unroll
    for (int kk = 0; kk < 2; ++kk)
#pragma unroll
      for (int nf = 0; nf < 4; ++nf) {
        int cc = nf * 16 + l15;
        int byo = ((cc * 64 + kk * 32 + lg * 8) * 2) ^ ((cc & 7) << 4);
        short8 bv = *(const short8*)((const char*)vt[cur] + byo);
#pragma unroll
        for (int i = 0; i < 2; ++i)
          of[i][nf] = __builtin_amdgcn_mfma_f32_16x16x32_bf16(apf[i][kk], bv, of[i][nf], 0, 0, 0);
      }
    __builtin_amdgcn_s_setprio(0);

    if (np) {
      *(u32x2*)((char*)vt[cur ^ 1] + vdstA[0]) = (u32x2){vreg0.x, vreg0.y};
      *(u32x2*)((char*)vt[cur ^ 1] + vdstB[0]) = (u32x2){vreg0.z, vreg0.w};
      *(u32x2*)((char*)vt[cur ^ 1] + vdstA[1]) = (u32x2){vreg1.x, vreg1.y};
      *(u32x2*)((char*)vt[cur ^ 1] + vdstB[1]) = (u32x2){vreg1.z, vreg1.w};
    }
    __syncthreads();
  }

  float linv[2][4];
#pragma unroll
  for (int i = 0; i < 2; ++i) {
    float ls = lp[i];
    ls += __shfl_xor(ls, 16);
    ls += __shfl_xor(ls, 32);
#pragma unroll
    for (int r = 0; r < 4; ++r)
      linv[i][r] = 1.0f / __shfl(ls, lg * 4 + r);
  }

#pragma unroll
  for (int i = 0; i < 2; ++i)
#pragma unroll
    for (int nf = 0; nf < 4; ++nf)
#pragma unroll
      for (int r = 0; r < 4; ++r) {
        int t = t0 + w * 32 + i * 16 + lg * 4 + r;
        int c = h * 64 + nf * 16 + l15;
        hb[((long)b * TSZ + t) * CCH + c] = f2bf(of[i][nf][r] * linv[i][r]);
      }
}

// ---------------- launch ----------------
extern "C" void kernel_launch(void* const* d_in, const int* in_sizes, int n_in,
                              void* d_out, int out_size, void* d_ws, size_t ws_size,
                              hipStream_t stream) {
  const float* x = (const float*)d_in[0];
  // d_in[1] = emb: unused by the reference
  const float* wq = (const float*)d_in[2];
  const float* bq = (const float*)d_in[3];
  const float* wp = (const float*)d_in[4];
  const float* bp = (const float*)d_in[5];

  char* ws = (char*)d_ws;
  short* wqb = (short*)ws;  ws += (long)1536 * 512 * 2;
  short* wpb = (short*)ws;  ws += (long)512 * 512 * 2;
  short* xnT = (short*)ws;  ws += (long)NBATCH * TSZ * CCH * 2;
  short* qkb = (short*)ws;  ws += (long)NBATCH * TSZ * 1024 * 2;
  short* vb  = (short*)ws;  ws += (long)NBATCH * CCH * TSZ * 2;
  short* hbuf = xnT;  // xnT dead after k_qkv; reuse for attention output

  k_cvt<<<4096, 256, 0, stream>>>(wq, wp, wqb, wpb);
  k_ln<<<dim3(NBATCH, 16), 256, 0, stream>>>(x, xnT);
  k_qkv<<<dim3(96, 16), 256, 0, stream>>>(xnT, wqb, qkb, vb, bq);
  k_attn<<<dim3(8, 128), 256, 0, stream>>>(qkb, vb, hbuf);
  k_proj<<<dim3(32, 16), 256, 0, stream>>>(wpb, hbuf, (float*)d_out, bp, x);
}

// Round 9
// 243.581 us; speedup vs baseline: 1.1247x; 1.1247x over previous
//
#include <hip/hip_runtime.h>

// AttentionBlock: B=16, C=512, H=W=32 (T=1024), 8 heads, head_dim=64, fp32 in/out.
// bf16 MFMA for matmul work, fp32 stats/softmax/accum. Residual path stays fp32.
// R9 = R7 (best known: no-max softmax attn, k-slot-permutation PV, dbuf attn
// staging, attn XCD swizzle) + ONE change: bijective XCD swizzle on the three
// k_gemm kernels (each XCD handles 2 batches; xnT[z]+weights fit its 4MB L2).
// No setprio, no GEMM dbuf, no kernel merge (R8 bundle regressed).

#define TSZ 1024
#define CCH 512
#define NBATCH 16

typedef __attribute__((ext_vector_type(8))) short short8;
typedef __attribute__((ext_vector_type(4))) float f32x4;
typedef __attribute__((ext_vector_type(4))) int i32x4;
typedef __attribute__((ext_vector_type(4))) unsigned u32x4;
typedef __attribute__((ext_vector_type(2))) unsigned u32x2;

__device__ inline short f2bf(float f) {
  unsigned u = __builtin_bit_cast(unsigned, f);
  u += 0x7fff + ((u >> 16) & 1);   // round-to-nearest-even
  return (short)(u >> 16);
}

__device__ inline void gl16(const void* g, void* l) {
  __builtin_amdgcn_global_load_lds((const __attribute__((address_space(1))) void*)g,
                                   (__attribute__((address_space(3))) void*)l,
                                   16, 0, 0);
}

// ---------------- weight fp32 -> bf16 ----------------
__global__ __launch_bounds__(256) void k_cvt(const float* __restrict__ wq,
                                             const float* __restrict__ wp,
                                             short* __restrict__ wqb,
                                             short* __restrict__ wpb) {
  int i = blockIdx.x * 256 + threadIdx.x;
  const int nq = 1536 * 512;
  if (i < nq) wqb[i] = f2bf(wq[i]);
  int j = i - nq;
  if (j >= 0 && j < 512 * 512) wpb[j] = f2bf(wp[j]);
}

// ---------------- LayerNorm over C + transpose to xnT[b][t][c] (bf16) ----------------
__global__ __launch_bounds__(256) void k_ln(const float* __restrict__ x,
                                            short* __restrict__ xnT) {
  const int b = blockIdx.x;
  const int t0 = blockIdx.y * 64;
  const int tid = threadIdx.x;
  const int tt = tid & 63, cg = tid >> 6;

  __shared__ float red[2][4][64];
  __shared__ float mu_s[64], rs_s[64];
  __shared__ float xt[64][65];   // +1 pad -> conflict-free transpose

  const float* xb = x + (long)b * CCH * TSZ;

  float s = 0.f, s2 = 0.f;
  for (int c = cg * 128; c < cg * 128 + 128; ++c) {
    float v = xb[(long)c * TSZ + t0 + tt];
    s += v; s2 += v * v;
  }
  red[0][cg][tt] = s; red[1][cg][tt] = s2;
  __syncthreads();
  if (tid < 64) {
    float ss = red[0][0][tid] + red[0][1][tid] + red[0][2][tid] + red[0][3][tid];
    float qq = red[1][0][tid] + red[1][1][tid] + red[1][2][tid] + red[1][3][tid];
    float mu = ss * (1.f / 512.f);
    float var = qq * (1.f / 512.f) - mu * mu;
    mu_s[tid] = mu;
    rs_s[tid] = rsqrtf(var + 1e-5f);
  }
  __syncthreads();

  for (int c0 = 0; c0 < CCH; c0 += 64) {
    for (int i = tid; i < 64 * 64; i += 256) {
      int ci = i >> 6, t2 = i & 63;
      xt[ci][t2] = xb[(long)(c0 + ci) * TSZ + t0 + t2];
    }
    __syncthreads();
    for (int i = tid; i < 64 * 64; i += 256) {
      int cc = i & 63, t2 = i >> 6;
      float v = (xt[cc][t2] - mu_s[t2]) * rs_s[t2];
      xnT[((long)b * TSZ + t0 + t2) * CCH + c0 + cc] = f2bf(v);
    }
    __syncthreads();
  }
}

// ---------------- head-aware W-row maps ----------------
__device__ inline int qkmap(int n) {        // qk output col -> w_qkv row
  if (n < 512) return (n >> 6) * 192 + (n & 63);          // q
  int j = n - 512;
  return (j >> 6) * 192 + 64 + (j & 63);                  // k
}
__device__ inline int vmap(int m) {         // v output row -> w_qkv row
  return (m >> 6) * 192 + 128 + (m & 63);
}

// ---------------- NT GEMM: C[m][n] = sum_k A[m][k]*B[n][k]  (128x128 tile, BK=32) ----
// MODE 0: qk = xnT x Wqk^T   -> bf16 out[b][t][1024], q cols scaled, +bias
// MODE 1: v  = Wv  x xnT^T   -> bf16 out[b][512][1024], +bias
// MODE 2: out= Wp  x hb^T    -> f32  out[b][512][1024], +bias +residual x
// R9: bijective XCD swizzle — each XCD handles 2 consecutive batches.
template <int MODE>
__global__ __launch_bounds__(256) void k_gemm(const short* __restrict__ Ab,
                                              const short* __restrict__ Bb,
                                              void* __restrict__ outb,
                                              const float* __restrict__ bias,
                                              const float* __restrict__ resid) {
  const int BPZ = (MODE == 0) ? 64 : 32;                 // blocks per batch
  const int d = (blockIdx.z * gridDim.y + blockIdx.y) * gridDim.x + blockIdx.x;
  const int orig = (d & 7) * (NBATCH * BPZ / 8) + (d >> 3);   // bijective
  const int b = orig / BPZ, wg = orig % BPZ;
  const int MB = (MODE == 0) ? 8 : 4;
  const int m0 = (wg % MB) * 128, n0 = (wg / MB) * 128;

  const int tid = threadIdx.x;
  const int lane = tid & 63, wv = tid >> 6;
  const int wm = wv >> 1, wn = wv & 1;
  const int l15 = lane & 15, lg = lane >> 4;

  const short* A = Ab + (MODE == 0 ? (long)b * TSZ * CCH : 0);
  const short* Bm = Bb + (MODE == 0 ? 0 : (long)b * TSZ * CCH);

  __shared__ __attribute__((aligned(16))) short sA[128 * 32];
  __shared__ __attribute__((aligned(16))) short sB[128 * 32];

  f32x4 acc[4][4];
#pragma unroll
  for (int i = 0; i < 4; ++i)
#pragma unroll
    for (int j = 0; j < 4; ++j) acc[i][j] = (f32x4){0.f, 0.f, 0.f, 0.f};

  long a_src[2], b_src[2];
#pragma unroll
  for (int q = 0; q < 2; ++q) {
    int idx = wv * 128 + q * 64 + lane;      // 16B chunk id, 512 total per tile
    int row = idx >> 2, kc = (idx & 3) * 8;  // 4 chunks per 32-elem row
    int am = m0 + row;
    int ar = (MODE == 1) ? vmap(am) : am;
    a_src[q] = (long)ar * CCH + kc;
    int bn = n0 + row;
    int br = (MODE == 0) ? qkmap(bn) : bn;
    b_src[q] = (long)br * CCH + kc;
  }

  for (int k0 = 0; k0 < CCH; k0 += 32) {
#pragma unroll
    for (int q = 0; q < 2; ++q) {
      gl16(A + a_src[q] + k0, sA + (wv * 128 + q * 64) * 8);
      gl16(Bm + b_src[q] + k0, sB + (wv * 128 + q * 64) * 8);
    }
    __syncthreads();
    short8 af[4], bfr[4];
#pragma unroll
    for (int i = 0; i < 4; ++i)
      af[i] = *(const short8*)(sA + ((wm * 64 + i * 16 + l15) * 32 + lg * 8));
#pragma unroll
    for (int j = 0; j < 4; ++j)
      bfr[j] = *(const short8*)(sB + ((wn * 64 + j * 16 + l15) * 32 + lg * 8));
#pragma unroll
    for (int i = 0; i < 4; ++i)
#pragma unroll
      for (int j = 0; j < 4; ++j)
        acc[i][j] = __builtin_amdgcn_mfma_f32_16x16x32_bf16(af[i], bfr[j], acc[i][j], 0, 0, 0);
    __syncthreads();
  }

#pragma unroll
  for (int i = 0; i < 4; ++i)
#pragma unroll
    for (int j = 0; j < 4; ++j)
#pragma unroll
      for (int r = 0; r < 4; ++r) {
        int mi = m0 + wm * 64 + i * 16 + lg * 4 + r;
        int ni = n0 + wn * 64 + j * 16 + l15;
        float val = acc[i][j][r];
        long o = (long)mi * TSZ + ni;
        if (MODE == 0) {
          val += bias[qkmap(ni)];
          // fold scale^2 = 1/8 AND log2(e) into q (post-bias, as ref):
          // attn kernel then uses exp2 directly.
          if (ni < 512) val *= 0.18033688011112042f;   // 0.125 * log2(e)
          ((short*)outb)[(long)b * TSZ * TSZ + o] = f2bf(val);
        } else if (MODE == 1) {
          val += bias[vmap(mi)];
          ((short*)outb)[(long)b * CCH * TSZ + o] = f2bf(val);
        } else {
          val += bias[mi] + resid[(long)b * CCH * TSZ + o];
          ((float*)outb)[(long)b * CCH * TSZ + o] = val;
        }
      }
}

// ---------------- flash attention (exact R7) ----------------
// no-max softmax, swapped QK, dbuf staging, XCD swizzle, P->PV via k-slot
// permutation (pure register), V sigma-permuted in LDS via reg-staging.
__global__ __launch_bounds__(256, 4) void k_attn(const short* __restrict__ qk,
                                                 const short* __restrict__ vbuf,
                                                 short* __restrict__ hb) {
  const int wgid = blockIdx.y * gridDim.x + blockIdx.x;   // 0..1023, x fastest
  const int xcd = wgid & 7, kb = wgid >> 3;
  const int bh = xcd * 16 + (kb & 15);                    // 16 bh per XCD
  const int t0 = (kb >> 4) * 128;
  const int b = bh >> 3, h = bh & 7;
  const int tid = threadIdx.x;
  const int lane = tid & 63, w = tid >> 6;
  const int l15 = lane & 15, lg = lane >> 4;

  __shared__ __attribute__((aligned(16))) short kt[2][64 * 64];   // [s][c], XOR swizzled
  __shared__ __attribute__((aligned(16))) short vt[2][64 * 64];   // [c][s'], sigma + swizzled

  const short* qkb = qk + (long)b * TSZ * 1024;
  const short* vb = vbuf + (long)b * CCH * TSZ;

  short8 aq[2][2];
  {
    const short* qb = qkb + (long)(t0 + w * 32) * 1024 + h * 64;
#pragma unroll
    for (int jt = 0; jt < 2; ++jt)
#pragma unroll
      for (int kk = 0; kk < 2; ++kk)
        aq[jt][kk] = *(const short8*)(qb + (long)(jt * 16 + l15) * 1024 + kk * 32 + lg * 8);
  }

  f32x4 of[2][4];
  float lp[2] = {0.f, 0.f};
#pragma unroll
  for (int i = 0; i < 2; ++i)
#pragma unroll
    for (int nf = 0; nf < 4; ++nf) of[i][nf] = (f32x4){0.f, 0.f, 0.f, 0.f};

  int srow[2], scoff[2];
#pragma unroll
  for (int q = 0; q < 2; ++q) {
    int idx = w * 128 + q * 64 + lane;
    int row = idx >> 3;
    int byo = ((idx & 7) * 16) ^ ((row & 7) << 4);
    srow[q] = row;
    scoff[q] = byo >> 1;
  }

  long vsrc[2];
  int vdstA[2], vdstB[2];
#pragma unroll
  for (int q = 0; q < 2; ++q) {
    int idx = q * 256 + tid;
    int c = idx >> 3, s8 = (idx & 7) * 8;
    vsrc[q] = (long)(h * 64 + c) * TSZ + s8;
    int kk2 = s8 >> 5, h4 = (s8 >> 4) & 1, lgf0 = (s8 & 15) >> 2;
    int spA = kk2 * 32 + lgf0 * 8 + h4 * 4;
    vdstA[q] = ((c * 64 + spA) * 2) ^ ((c & 7) << 4);
    vdstB[q] = ((c * 64 + spA + 8) * 2) ^ ((c & 7) << 4);
  }

#define STAGE_K(buf, s0s)                                                      \
  {                                                                            \
    _Pragma("unroll") for (int q = 0; q < 2; ++q)                              \
      gl16(qkb + (long)((s0s) + srow[q]) * 1024 + 512 + h * 64 + scoff[q],     \
           kt[buf] + (w * 128 + q * 64) * 8);                                  \
  }

  u32x4 vreg0 = *(const u32x4*)(vb + vsrc[0]);
  u32x4 vreg1 = *(const u32x4*)(vb + vsrc[1]);
  STAGE_K(0, 0);
  *(u32x2*)((char*)vt[0] + vdstA[0]) = (u32x2){vreg0.x, vreg0.y};
  *(u32x2*)((char*)vt[0] + vdstB[0]) = (u32x2){vreg0.z, vreg0.w};
  *(u32x2*)((char*)vt[0] + vdstA[1]) = (u32x2){vreg1.x, vreg1.y};
  *(u32x2*)((char*)vt[0] + vdstB[1]) = (u32x2){vreg1.z, vreg1.w};
  __syncthreads();

  for (int s0 = 0; s0 < TSZ; s0 += 64) {
    const int cur = (s0 >> 6) & 1;
    const bool np = (s0 + 64 < TSZ);
    if (np) {
      vreg0 = *(const u32x4*)(vb + vsrc[0] + s0 + 64);
      vreg1 = *(const u32x4*)(vb + vsrc[1] + s0 + 64);
      STAGE_K(cur ^ 1, s0 + 64);
    }

    // S^T = K Q^T via mfma(K,Q): lane holds S[s=ms*16+lg*4+r][t=jt*16+l15]
    f32x4 sf[2][4];
#pragma unroll
    for (int jt = 0; jt < 2; ++jt)
#pragma unroll
      for (int ms = 0; ms < 4; ++ms) sf[jt][ms] = (f32x4){0.f, 0.f, 0.f, 0.f};
#pragma unroll
    for (int kk = 0; kk < 2; ++kk)
#pragma unroll
      for (int ms = 0; ms < 4; ++ms) {
        int srw = ms * 16 + l15;
        int byo = ((srw * 64 + kk * 32 + lg * 8) * 2) ^ ((srw & 7) << 4);
        short8 ka = *(const short8*)((const char*)kt[cur] + byo);
#pragma unroll
        for (int jt = 0; jt < 2; ++jt)
          sf[jt][ms] = __builtin_amdgcn_mfma_f32_16x16x32_bf16(ka, aq[jt][kk], sf[jt][ms], 0, 0, 0);
      }

    // p = 2^s; denom in-lane; cvt_pk pairs ARE the PV A-fragment under pi.
    short8 apf[2][2];
#pragma unroll
    for (int jt = 0; jt < 2; ++jt) {
      float p[4][4];
#pragma unroll
      for (int ms = 0; ms < 4; ++ms)
#pragma unroll
        for (int r = 0; r < 4; ++r)
          p[ms][r] = exp2f(sf[jt][ms][r]);
#pragma unroll
      for (int ms = 0; ms < 4; ++ms)
        lp[jt] += (p[ms][0] + p[ms][1]) + (p[ms][2] + p[ms][3]);
      unsigned pk[4][2];
#pragma unroll
      for (int ms = 0; ms < 4; ++ms)
#pragma unroll
        for (int u = 0; u < 2; ++u)
          asm("v_cvt_pk_bf16_f32 %0, %1, %2" : "=v"(pk[ms][u])
              : "v"(p[ms][2 * u]), "v"(p[ms][2 * u + 1]));
#pragma unroll
      for (int kk = 0; kk < 2; ++kk) {
        i32x4 a32 = (i32x4){(int)pk[2 * kk][0], (int)pk[2 * kk][1],
                            (int)pk[2 * kk + 1][0], (int)pk[2 * kk + 1][1]};
        apf[jt][kk] = __builtin_bit_cast(short8, a32);
      }
    }

    // O += P V^T  (M=t, N=c, K=s) ; V read supplies pi-permuted k-slots
#pragma unroll
    for (int kk = 0; kk < 2; ++kk)
#pragma unroll
      for (int nf = 0; nf < 4; ++nf) {
        int cc = nf * 16 + l15;
        int byo = ((cc * 64 + kk * 32 + lg * 8) * 2) ^ ((cc & 7) << 4);
        short8 bv = *(const short8*)((const char*)vt[cur] + byo);
#pragma unroll
        for (int i = 0; i < 2; ++i)
          of[i][nf] = __builtin_amdgcn_mfma_f32_16x16x32_bf16(apf[i][kk], bv, of[i][nf], 0, 0, 0);
      }

    if (np) {
      *(u32x2*)((char*)vt[cur ^ 1] + vdstA[0]) = (u32x2){vreg0.x, vreg0.y};
      *(u32x2*)((char*)vt[cur ^ 1] + vdstB[0]) = (u32x2){vreg0.z, vreg0.w};
      *(u32x2*)((char*)vt[cur ^ 1] + vdstA[1]) = (u32x2){vreg1.x, vreg1.y};
      *(u32x2*)((char*)vt[cur ^ 1] + vdstB[1]) = (u32x2){vreg1.z, vreg1.w};
    }
    __syncthreads();
  }

  float linv[2][4];
#pragma unroll
  for (int i = 0; i < 2; ++i) {
    float ls = lp[i];
    ls += __shfl_xor(ls, 16);
    ls += __shfl_xor(ls, 32);
#pragma unroll
    for (int r = 0; r < 4; ++r)
      linv[i][r] = 1.0f / __shfl(ls, lg * 4 + r);
  }

#pragma unroll
  for (int i = 0; i < 2; ++i)
#pragma unroll
    for (int nf = 0; nf < 4; ++nf)
#pragma unroll
      for (int r = 0; r < 4; ++r) {
        int t = t0 + w * 32 + i * 16 + lg * 4 + r;
        int c = h * 64 + nf * 16 + l15;
        hb[((long)b * TSZ + t) * CCH + c] = f2bf(of[i][nf][r] * linv[i][r]);
      }
}

// ---------------- launch ----------------
extern "C" void kernel_launch(void* const* d_in, const int* in_sizes, int n_in,
                              void* d_out, int out_size, void* d_ws, size_t ws_size,
                              hipStream_t stream) {
  const float* x = (const float*)d_in[0];
  // d_in[1] = emb: unused by the reference
  const float* wq = (const float*)d_in[2];
  const float* bq = (const float*)d_in[3];
  const float* wp = (const float*)d_in[4];
  const float* bp = (const float*)d_in[5];

  char* ws = (char*)d_ws;
  short* wqb = (short*)ws;  ws += (long)1536 * 512 * 2;
  short* wpb = (short*)ws;  ws += (long)512 * 512 * 2;
  short* xnT = (short*)ws;  ws += (long)NBATCH * TSZ * CCH * 2;
  short* qkb = (short*)ws;  ws += (long)NBATCH * TSZ * 1024 * 2;
  short* vb  = (short*)ws;  ws += (long)NBATCH * CCH * TSZ * 2;
  short* hbuf = xnT;  // xnT dead after k_gemm<1>; reuse for attention output

  k_cvt<<<4096, 256, 0, stream>>>(wq, wp, wqb, wpb);
  k_ln<<<dim3(NBATCH, 16), 256, 0, stream>>>(x, xnT);
  k_gemm<0><<<dim3(8, 8, NBATCH), 256, 0, stream>>>(xnT, wqb, qkb, bq, nullptr);
  k_gemm<1><<<dim3(4, 8, NBATCH), 256, 0, stream>>>(wqb, xnT, vb, bq, nullptr);
  k_attn<<<dim3(8, 128), 256, 0, stream>>>(qkb, vb, hbuf);
  k_gemm<2><<<dim3(4, 8, NBATCH), 256, 0, stream>>>(wpb, hbuf, d_out, bp, x);
}

// Round 11
// 232.145 us; speedup vs baseline: 1.1801x; 1.0493x over previous
//
#include <hip/hip_runtime.h>

// AttentionBlock: B=16, C=512, H=W=32 (T=1024), 8 heads, head_dim=64, fp32 in/out.
// bf16 MFMA for matmul work, fp32 stats/softmax/accum. Residual path stays fp32.
// R11 = R10 with the exp fixed: raw v_exp_f32 via __builtin_amdgcn_exp2f
// (compiler handles the TRANS-op wait-state hazard that R10's bare inline asm
// violated -> NaN). Fallback asm embeds s_nop 1. Hoisted staging ptrs kept.

#define TSZ 1024
#define CCH 512
#define NBATCH 16

typedef __attribute__((ext_vector_type(8))) short short8;
typedef __attribute__((ext_vector_type(4))) float f32x4;
typedef __attribute__((ext_vector_type(4))) int i32x4;
typedef __attribute__((ext_vector_type(4))) unsigned u32x4;
typedef __attribute__((ext_vector_type(2))) unsigned u32x2;

__device__ inline short f2bf(float f) {
  unsigned u = __builtin_bit_cast(unsigned, f);
  u += 0x7fff + ((u >> 16) & 1);   // round-to-nearest-even
  return (short)(u >> 16);
}

__device__ inline float fexp2(float x) {   // bare 2^x, hazard-safe
#if __has_builtin(__builtin_amdgcn_exp2f)
  return __builtin_amdgcn_exp2f(x);
#else
  float r;
  asm volatile("v_exp_f32 %0, %1\n\ts_nop 1" : "=v"(r) : "v"(x));
  return r;
#endif
}

__device__ inline void gl16(const void* g, void* l) {
  __builtin_amdgcn_global_load_lds((const __attribute__((address_space(1))) void*)g,
                                   (__attribute__((address_space(3))) void*)l,
                                   16, 0, 0);
}

// ---------------- weight fp32 -> bf16 ----------------
__global__ __launch_bounds__(256) void k_cvt(const float* __restrict__ wq,
                                             const float* __restrict__ wp,
                                             short* __restrict__ wqb,
                                             short* __restrict__ wpb) {
  int i = blockIdx.x * 256 + threadIdx.x;
  const int nq = 1536 * 512;
  if (i < nq) wqb[i] = f2bf(wq[i]);
  int j = i - nq;
  if (j >= 0 && j < 512 * 512) wpb[j] = f2bf(wp[j]);
}

// ---------------- LayerNorm over C + transpose to xnT[b][t][c] (bf16) ----------------
__global__ __launch_bounds__(256) void k_ln(const float* __restrict__ x,
                                            short* __restrict__ xnT) {
  const int b = blockIdx.x;
  const int t0 = blockIdx.y * 64;
  const int tid = threadIdx.x;
  const int tt = tid & 63, cg = tid >> 6;

  __shared__ float red[2][4][64];
  __shared__ float mu_s[64], rs_s[64];
  __shared__ float xt[64][65];   // +1 pad -> conflict-free transpose

  const float* xb = x + (long)b * CCH * TSZ;

  float s = 0.f, s2 = 0.f;
  for (int c = cg * 128; c < cg * 128 + 128; ++c) {
    float v = xb[(long)c * TSZ + t0 + tt];
    s += v; s2 += v * v;
  }
  red[0][cg][tt] = s; red[1][cg][tt] = s2;
  __syncthreads();
  if (tid < 64) {
    float ss = red[0][0][tid] + red[0][1][tid] + red[0][2][tid] + red[0][3][tid];
    float qq = red[1][0][tid] + red[1][1][tid] + red[1][2][tid] + red[1][3][tid];
    float mu = ss * (1.f / 512.f);
    float var = qq * (1.f / 512.f) - mu * mu;
    mu_s[tid] = mu;
    rs_s[tid] = rsqrtf(var + 1e-5f);
  }
  __syncthreads();

  for (int c0 = 0; c0 < CCH; c0 += 64) {
    for (int i = tid; i < 64 * 64; i += 256) {
      int ci = i >> 6, t2 = i & 63;
      xt[ci][t2] = xb[(long)(c0 + ci) * TSZ + t0 + t2];
    }
    __syncthreads();
    for (int i = tid; i < 64 * 64; i += 256) {
      int cc = i & 63, t2 = i >> 6;
      float v = (xt[cc][t2] - mu_s[t2]) * rs_s[t2];
      xnT[((long)b * TSZ + t0 + t2) * CCH + c0 + cc] = f2bf(v);
    }
    __syncthreads();
  }
}

// ---------------- head-aware W-row maps ----------------
__device__ inline int qkmap(int n) {        // qk output col -> w_qkv row
  if (n < 512) return (n >> 6) * 192 + (n & 63);          // q
  int j = n - 512;
  return (j >> 6) * 192 + 64 + (j & 63);                  // k
}
__device__ inline int vmap(int m) {         // v output row -> w_qkv row
  return (m >> 6) * 192 + 128 + (m & 63);
}

// ---------------- NT GEMM: C[m][n] = sum_k A[m][k]*B[n][k]  (128x128 tile, BK=32) ----
// MODE 0: qk = xnT x Wqk^T   -> bf16 out[b][t][1024], q cols scaled, +bias
// MODE 1: v  = Wv  x xnT^T   -> bf16 out[b][512][1024], +bias
// MODE 2: out= Wp  x hb^T    -> f32  out[b][512][1024], +bias +residual x
template <int MODE>
__global__ __launch_bounds__(256) void k_gemm(const short* __restrict__ Ab,
                                              const short* __restrict__ Bb,
                                              void* __restrict__ outb,
                                              const float* __restrict__ bias,
                                              const float* __restrict__ resid) {
  const int BPZ = (MODE == 0) ? 64 : 32;                 // blocks per batch
  const int d = (blockIdx.z * gridDim.y + blockIdx.y) * gridDim.x + blockIdx.x;
  const int orig = (d & 7) * (NBATCH * BPZ / 8) + (d >> 3);   // bijective
  const int b = orig / BPZ, wg = orig % BPZ;
  const int MB = (MODE == 0) ? 8 : 4;
  const int m0 = (wg % MB) * 128, n0 = (wg / MB) * 128;

  const int tid = threadIdx.x;
  const int lane = tid & 63, wv = tid >> 6;
  const int wm = wv >> 1, wn = wv & 1;
  const int l15 = lane & 15, lg = lane >> 4;

  const short* A = Ab + (MODE == 0 ? (long)b * TSZ * CCH : 0);
  const short* Bm = Bb + (MODE == 0 ? 0 : (long)b * TSZ * CCH);

  __shared__ __attribute__((aligned(16))) short sA[128 * 32];
  __shared__ __attribute__((aligned(16))) short sB[128 * 32];

  f32x4 acc[4][4];
#pragma unroll
  for (int i = 0; i < 4; ++i)
#pragma unroll
    for (int j = 0; j < 4; ++j) acc[i][j] = (f32x4){0.f, 0.f, 0.f, 0.f};

  long a_src[2], b_src[2];
#pragma unroll
  for (int q = 0; q < 2; ++q) {
    int idx = wv * 128 + q * 64 + lane;      // 16B chunk id, 512 total per tile
    int row = idx >> 2, kc = (idx & 3) * 8;  // 4 chunks per 32-elem row
    int am = m0 + row;
    int ar = (MODE == 1) ? vmap(am) : am;
    a_src[q] = (long)ar * CCH + kc;
    int bn = n0 + row;
    int br = (MODE == 0) ? qkmap(bn) : bn;
    b_src[q] = (long)br * CCH + kc;
  }

  for (int k0 = 0; k0 < CCH; k0 += 32) {
#pragma unroll
    for (int q = 0; q < 2; ++q) {
      gl16(A + a_src[q] + k0, sA + (wv * 128 + q * 64) * 8);
      gl16(Bm + b_src[q] + k0, sB + (wv * 128 + q * 64) * 8);
    }
    __syncthreads();
    short8 af[4], bfr[4];
#pragma unroll
    for (int i = 0; i < 4; ++i)
      af[i] = *(const short8*)(sA + ((wm * 64 + i * 16 + l15) * 32 + lg * 8));
#pragma unroll
    for (int j = 0; j < 4; ++j)
      bfr[j] = *(const short8*)(sB + ((wn * 64 + j * 16 + l15) * 32 + lg * 8));
#pragma unroll
    for (int i = 0; i < 4; ++i)
#pragma unroll
      for (int j = 0; j < 4; ++j)
        acc[i][j] = __builtin_amdgcn_mfma_f32_16x16x32_bf16(af[i], bfr[j], acc[i][j], 0, 0, 0);
    __syncthreads();
  }

#pragma unroll
  for (int i = 0; i < 4; ++i)
#pragma unroll
    for (int j = 0; j < 4; ++j)
#pragma unroll
      for (int r = 0; r < 4; ++r) {
        int mi = m0 + wm * 64 + i * 16 + lg * 4 + r;
        int ni = n0 + wn * 64 + j * 16 + l15;
        float val = acc[i][j][r];
        long o = (long)mi * TSZ + ni;
        if (MODE == 0) {
          val += bias[qkmap(ni)];
          // fold scale^2 = 1/8 AND log2(e) into q (post-bias, as ref):
          // attn kernel then uses exp2 directly.
          if (ni < 512) val *= 0.18033688011112042f;   // 0.125 * log2(e)
          ((short*)outb)[(long)b * TSZ * TSZ + o] = f2bf(val);
        } else if (MODE == 1) {
          val += bias[vmap(mi)];
          ((short*)outb)[(long)b * CCH * TSZ + o] = f2bf(val);
        } else {
          val += bias[mi] + resid[(long)b * CCH * TSZ + o];
          ((float*)outb)[(long)b * CCH * TSZ + o] = val;
        }
      }
}

// ---------------- flash attention ----------------
// no-max softmax, swapped QK, dbuf staging, XCD swizzle, P->PV via k-slot
// permutation (pure register), V sigma-permuted in LDS via reg-staging.
// R11: hazard-safe bare exp2 + hoisted staging base pointers.
__global__ __launch_bounds__(256, 4) void k_attn(const short* __restrict__ qk,
                                                 const short* __restrict__ vbuf,
                                                 short* __restrict__ hb) {
  const int wgid = blockIdx.y * gridDim.x + blockIdx.x;   // 0..1023, x fastest
  const int xcd = wgid & 7, kb = wgid >> 3;
  const int bh = xcd * 16 + (kb & 15);                    // 16 bh per XCD
  const int t0 = (kb >> 4) * 128;
  const int b = bh >> 3, h = bh & 7;
  const int tid = threadIdx.x;
  const int lane = tid & 63, w = tid >> 6;
  const int l15 = lane & 15, lg = lane >> 4;

  __shared__ __attribute__((aligned(16))) short kt[2][64 * 64];   // [s][c], XOR swizzled
  __shared__ __attribute__((aligned(16))) short vt[2][64 * 64];   // [c][s'], sigma + swizzled

  const short* qkb = qk + (long)b * TSZ * 1024;
  const short* vb = vbuf + (long)b * CCH * TSZ;

  short8 aq[2][2];
  {
    const short* qb = qkb + (long)(t0 + w * 32) * 1024 + h * 64;
#pragma unroll
    for (int jt = 0; jt < 2; ++jt)
#pragma unroll
      for (int kk = 0; kk < 2; ++kk)
        aq[jt][kk] = *(const short8*)(qb + (long)(jt * 16 + l15) * 1024 + kk * 32 + lg * 8);
  }

  f32x4 of[2][4];
  float lp[2] = {0.f, 0.f};
#pragma unroll
  for (int i = 0; i < 2; ++i)
#pragma unroll
    for (int nf = 0; nf < 4; ++nf) of[i][nf] = (f32x4){0.f, 0.f, 0.f, 0.f};

  // hoisted per-thread staging base pointers (advance by fixed stride per tile)
  const short* ksrc[2];
  const short* vsrcp[2];
  int kdst[2], vdstA[2], vdstB[2];
#pragma unroll
  for (int q = 0; q < 2; ++q) {
    {  // K: 16B chunk id, 512 per 8KB tile; pre-swizzled source
      int idx = w * 128 + q * 64 + lane;
      int row = idx >> 3;
      int byo = ((idx & 7) * 16) ^ ((row & 7) << 4);
      ksrc[q] = qkb + (long)row * 1024 + 512 + h * 64 + (byo >> 1);
      kdst[q] = (w * 128 + q * 64) * 8;
    }
    {  // V: sigma-permuted LDS dest, linear global source
      int idx = q * 256 + tid;
      int c = idx >> 3, s8 = (idx & 7) * 8;
      vsrcp[q] = vb + (long)(h * 64 + c) * TSZ + s8;
      int kk2 = s8 >> 5, h4 = (s8 >> 4) & 1, lgf0 = (s8 & 15) >> 2;
      int spA = kk2 * 32 + lgf0 * 8 + h4 * 4;
      vdstA[q] = ((c * 64 + spA) * 2) ^ ((c & 7) << 4);
      vdstB[q] = ((c * 64 + spA + 8) * 2) ^ ((c & 7) << 4);
    }
  }

#define STAGE_K(buf, s0s)                                                      \
  {                                                                            \
    _Pragma("unroll") for (int q = 0; q < 2; ++q)                              \
      gl16(ksrc[q] + (long)(s0s) * 1024, kt[buf] + kdst[q]);                   \
  }

  u32x4 vreg0 = *(const u32x4*)(vsrcp[0]);
  u32x4 vreg1 = *(const u32x4*)(vsrcp[1]);
  STAGE_K(0, 0);
  *(u32x2*)((char*)vt[0] + vdstA[0]) = (u32x2){vreg0.x, vreg0.y};
  *(u32x2*)((char*)vt[0] + vdstB[0]) = (u32x2){vreg0.z, vreg0.w};
  *(u32x2*)((char*)vt[0] + vdstA[1]) = (u32x2){vreg1.x, vreg1.y};
  *(u32x2*)((char*)vt[0] + vdstB[1]) = (u32x2){vreg1.z, vreg1.w};
  __syncthreads();

  for (int s0 = 0; s0 < TSZ; s0 += 64) {
    const int cur = (s0 >> 6) & 1;
    const bool np = (s0 + 64 < TSZ);
    if (np) {
      vreg0 = *(const u32x4*)(vsrcp[0] + s0 + 64);
      vreg1 = *(const u32x4*)(vsrcp[1] + s0 + 64);
      STAGE_K(cur ^ 1, s0 + 64);
    }

    // S^T = K Q^T via mfma(K,Q): lane holds S[s=ms*16+lg*4+r][t=jt*16+l15]
    f32x4 sf[2][4];
#pragma unroll
    for (int jt = 0; jt < 2; ++jt)
#pragma unroll
      for (int ms = 0; ms < 4; ++ms) sf[jt][ms] = (f32x4){0.f, 0.f, 0.f, 0.f};
#pragma unroll
    for (int kk = 0; kk < 2; ++kk)
#pragma unroll
      for (int ms = 0; ms < 4; ++ms) {
        int srw = ms * 16 + l15;
        int byo = ((srw * 64 + kk * 32 + lg * 8) * 2) ^ ((srw & 7) << 4);
        short8 ka = *(const short8*)((const char*)kt[cur] + byo);
#pragma unroll
        for (int jt = 0; jt < 2; ++jt)
          sf[jt][ms] = __builtin_amdgcn_mfma_f32_16x16x32_bf16(ka, aq[jt][kk], sf[jt][ms], 0, 0, 0);
      }

    // p = 2^s; denom in-lane; cvt_pk pairs ARE the PV A-fragment under pi.
    short8 apf[2][2];
#pragma unroll
    for (int jt = 0; jt < 2; ++jt) {
      float p[4][4];
#pragma unroll
      for (int ms = 0; ms < 4; ++ms)
#pragma unroll
        for (int r = 0; r < 4; ++r)
          p[ms][r] = fexp2(sf[jt][ms][r]);
#pragma unroll
      for (int ms = 0; ms < 4; ++ms)
        lp[jt] += (p[ms][0] + p[ms][1]) + (p[ms][2] + p[ms][3]);
      unsigned pk[4][2];
#pragma unroll
      for (int ms = 0; ms < 4; ++ms)
#pragma unroll
        for (int u = 0; u < 2; ++u)
          asm("v_cvt_pk_bf16_f32 %0, %1, %2" : "=v"(pk[ms][u])
              : "v"(p[ms][2 * u]), "v"(p[ms][2 * u + 1]));
#pragma unroll
      for (int kk = 0; kk < 2; ++kk) {
        i32x4 a32 = (i32x4){(int)pk[2 * kk][0], (int)pk[2 * kk][1],
                            (int)pk[2 * kk + 1][0], (int)pk[2 * kk + 1][1]};
        apf[jt][kk] = __builtin_bit_cast(short8, a32);
      }
    }

    // O += P V^T  (M=t, N=c, K=s) ; V read supplies pi-permuted k-slots
#pragma unroll
    for (int kk = 0; kk < 2; ++kk)
#pragma unroll
      for (int nf = 0; nf < 4; ++nf) {
        int cc = nf * 16 + l15;
        int byo = ((cc * 64 + kk * 32 + lg * 8) * 2) ^ ((cc & 7) << 4);
        short8 bv = *(const short8*)((const char*)vt[cur] + byo);
#pragma unroll
        for (int i = 0; i < 2; ++i)
          of[i][nf] = __builtin_amdgcn_mfma_f32_16x16x32_bf16(apf[i][kk], bv, of[i][nf], 0, 0, 0);
      }

    if (np) {
      *(u32x2*)((char*)vt[cur ^ 1] + vdstA[0]) = (u32x2){vreg0.x, vreg0.y};
      *(u32x2*)((char*)vt[cur ^ 1] + vdstB[0]) = (u32x2){vreg0.z, vreg0.w};
      *(u32x2*)((char*)vt[cur ^ 1] + vdstA[1]) = (u32x2){vreg1.x, vreg1.y};
      *(u32x2*)((char*)vt[cur ^ 1] + vdstB[1]) = (u32x2){vreg1.z, vreg1.w};
    }
    __syncthreads();
  }

  float linv[2][4];
#pragma unroll
  for (int i = 0; i < 2; ++i) {
    float ls = lp[i];
    ls += __shfl_xor(ls, 16);
    ls += __shfl_xor(ls, 32);
#pragma unroll
    for (int r = 0; r < 4; ++r)
      linv[i][r] = 1.0f / __shfl(ls, lg * 4 + r);
  }

#pragma unroll
  for (int i = 0; i < 2; ++i)
#pragma unroll
    for (int nf = 0; nf < 4; ++nf)
#pragma unroll
      for (int r = 0; r < 4; ++r) {
        int t = t0 + w * 32 + i * 16 + lg * 4 + r;
        int c = h * 64 + nf * 16 + l15;
        hb[((long)b * TSZ + t) * CCH + c] = f2bf(of[i][nf][r] * linv[i][r]);
      }
}

// ---------------- launch ----------------
extern "C" void kernel_launch(void* const* d_in, const int* in_sizes, int n_in,
                              void* d_out, int out_size, void* d_ws, size_t ws_size,
                              hipStream_t stream) {
  const float* x = (const float*)d_in[0];
  // d_in[1] = emb: unused by the reference
  const float* wq = (const float*)d_in[2];
  const float* bq = (const float*)d_in[3];
  const float* wp = (const float*)d_in[4];
  const float* bp = (const float*)d_in[5];

  char* ws = (char*)d_ws;
  short* wqb = (short*)ws;  ws += (long)1536 * 512 * 2;
  short* wpb = (short*)ws;  ws += (long)512 * 512 * 2;
  short* xnT = (short*)ws;  ws += (long)NBATCH * TSZ * CCH * 2;
  short* qkb = (short*)ws;  ws += (long)NBATCH * TSZ * 1024 * 2;
  short* vb  = (short*)ws;  ws += (long)NBATCH * CCH * TSZ * 2;
  short* hbuf = xnT;  // xnT dead after k_gemm<1>; reuse for attention output

  k_cvt<<<4096, 256, 0, stream>>>(wq, wp, wqb, wpb);
  k_ln<<<dim3(NBATCH, 16), 256, 0, stream>>>(x, xnT);
  k_gemm<0><<<dim3(8, 8, NBATCH), 256, 0, stream>>>(xnT, wqb, qkb, bq, nullptr);
  k_gemm<1><<<dim3(4, 8, NBATCH), 256, 0, stream>>>(wqb, xnT, vb, bq, nullptr);
  k_attn<<<dim3(8, 128), 256, 0, stream>>>(qkb, vb, hbuf);
  k_gemm<2><<<dim3(4, 8, NBATCH), 256, 0, stream>>>(wpb, hbuf, d_out, bp, x);
}